// Round 1
// baseline (400.743 us; speedup 1.0000x reference)
//
#include <hip/hip_runtime.h>

#define TSEQ 4096
#define BATCH 2
#define DM 512
#define NH 8
#define HS 64
#define CTX 256

// ---------------------------------------------------------------------------
// Kernel 1: QV projection.
// Virtual output [B*T=8192, 1024]: cols 0..511 = Q (head = c/64), 512..1023 = V.
// 64x64 tile per block, 256 threads, 4x4 micro-tile per thread.
// ---------------------------------------------------------------------------
__global__ __launch_bounds__(256) void qv_proj_kernel(
    const float* __restrict__ X,   // [8192, 512]
    const float* __restrict__ WQ,  // [8, 512, 64]
    const float* __restrict__ WV,  // [8, 512, 64]
    float* __restrict__ Q,         // [B, H, T, 64]
    float* __restrict__ V)         // [B, H, T, 64]
{
    __shared__ float As[32][72];   // [k][row] (X^T chunk), padded, 16B-aligned rows
    __shared__ float Bs[32][68];   // [k][col]

    const int tid = threadIdx.x;
    const int tx = tid & 15, ty = tid >> 4;
    const int r0 = blockIdx.x * 64;
    const int cblk = blockIdx.y;           // 0..15
    const bool isQ = (cblk < NH);
    const int h = isQ ? cblk : cblk - NH;
    const float* W = (isQ ? WQ : WV) + (size_t)h * DM * HS;  // [512][64]

    float acc[4][4] = {};

    for (int k0 = 0; k0 < DM; k0 += 32) {
        // A: X[r0+row][k0+kk] -> As[kk][row]
        #pragma unroll
        for (int i = 0; i < 2; ++i) {
            int idx = tid + i * 256;           // 0..511
            int row = idx >> 3;                // 0..63
            int kk  = (idx & 7) * 4;
            float4 a = *(const float4*)(X + (size_t)(r0 + row) * DM + k0 + kk);
            As[kk + 0][row] = a.x; As[kk + 1][row] = a.y;
            As[kk + 2][row] = a.z; As[kk + 3][row] = a.w;
        }
        // B: W[k0+kk][c] -> Bs[kk][c]  (contiguous in c)
        #pragma unroll
        for (int i = 0; i < 2; ++i) {
            int idx = tid + i * 256;
            int kk = idx >> 4;                 // 0..31
            int c  = (idx & 15) * 4;
            *(float4*)&Bs[kk][c] = *(const float4*)(W + (size_t)(k0 + kk) * HS + c);
        }
        __syncthreads();

        #pragma unroll
        for (int k = 0; k < 32; ++k) {
            float4 a4 = *(const float4*)&As[k][ty * 4];
            float4 b4 = *(const float4*)&Bs[k][tx * 4];
            float av[4] = {a4.x, a4.y, a4.z, a4.w};
            float bv[4] = {b4.x, b4.y, b4.z, b4.w};
            #pragma unroll
            for (int i = 0; i < 4; ++i)
                #pragma unroll
                for (int j = 0; j < 4; ++j)
                    acc[i][j] = fmaf(av[i], bv[j], acc[i][j]);
        }
        __syncthreads();
    }

    float* O = isQ ? Q : V;
    #pragma unroll
    for (int i = 0; i < 4; ++i) {
        int r = r0 + ty * 4 + i;
        int b = r >> 12, t = r & (TSEQ - 1);
        float4 v4 = make_float4(acc[i][0], acc[i][1], acc[i][2], acc[i][3]);
        *(float4*)(O + (((size_t)(b * NH + h) * TSEQ + t) * HS) + tx * 4) = v4;
    }
}

// ---------------------------------------------------------------------------
// Kernel 2: banded flash attention (f32).
// One block per (b, h, 64-row t-tile). scores = (Q/8) @ V^T, band |t-u|<=256,
// online softmax, C = W @ V. C stored [B, T, H, S] (heads pre-concatenated).
// ---------------------------------------------------------------------------
__global__ __launch_bounds__(256) void attn_kernel(
    const float* __restrict__ Q,   // [B, H, T, 64]
    const float* __restrict__ V,   // [B, H, T, 64]
    float* __restrict__ C)         // [B, T, H, 64]
{
    __shared__ float Qs[64][68];   // [s][t]  Q^T, prescaled by 1/8
    __shared__ float VsT[64][68];  // [s][u]  V^T
    __shared__ float Vs[64][68];   // [u][s]  V
    __shared__ float Ps[64][68];   // [u][t]  P^T

    const int tid = threadIdx.x;
    const int tx = tid & 15, ty = tid >> 4;
    const int blk = blockIdx.x;
    const int t0 = (blk & 63) * 64;        // T/64 = 64 tiles
    const int bh = blk >> 6;               // b*8 + h
    const int h = bh & 7, b = bh >> 3;
    const float* Qp = Q + (size_t)bh * TSEQ * HS;
    const float* Vp = V + (size_t)bh * TSEQ * HS;

    // Load Q tile transposed + prescale. t-major lanes -> conflict-free writes.
    #pragma unroll
    for (int i = 0; i < 4; ++i) {
        int idx = tid + i * 256;           // 0..1023
        int tt = idx & 63;
        int sb = (idx >> 6) * 4;           // 0,4,...,60
        float4 q4 = *(const float4*)(Qp + (size_t)(t0 + tt) * HS + sb);
        Qs[sb + 0][tt] = q4.x * 0.125f;
        Qs[sb + 1][tt] = q4.y * 0.125f;
        Qs[sb + 2][tt] = q4.z * 0.125f;
        Qs[sb + 3][tt] = q4.w * 0.125f;
    }

    float o[4][4] = {};
    float m[4], l[4];
    #pragma unroll
    for (int i = 0; i < 4; ++i) { m[i] = -1e30f; l[i] = 0.f; }

    int u_lo = t0 - CTX; if (u_lo < 0) u_lo = 0;
    int u_hi = t0 + 64 + CTX; if (u_hi > TSEQ) u_hi = TSEQ;

    for (int u0 = u_lo; u0 < u_hi; u0 += 64) {
        __syncthreads();   // protect LDS buffers from previous iteration's readers

        // Load V chunk in both layouts (t-major lanes -> conflict-free VsT writes)
        #pragma unroll
        for (int i = 0; i < 4; ++i) {
            int idx = tid + i * 256;
            int uu = idx & 63;
            int sb = (idx >> 6) * 4;
            float4 v4 = *(const float4*)(Vp + (size_t)(u0 + uu) * HS + sb);
            VsT[sb + 0][uu] = v4.x; VsT[sb + 1][uu] = v4.y;
            VsT[sb + 2][uu] = v4.z; VsT[sb + 3][uu] = v4.w;
            *(float4*)&Vs[uu][sb] = v4;
        }
        __syncthreads();

        // scores S[t][u] = sum_s Qs[s][t] * VsT[s][u]
        float sa[4][4] = {};
        #pragma unroll
        for (int k = 0; k < 64; ++k) {
            float4 a4 = *(const float4*)&Qs[k][ty * 4];
            float4 b4 = *(const float4*)&VsT[k][tx * 4];
            float av[4] = {a4.x, a4.y, a4.z, a4.w};
            float bv[4] = {b4.x, b4.y, b4.z, b4.w};
            #pragma unroll
            for (int i = 0; i < 4; ++i)
                #pragma unroll
                for (int j = 0; j < 4; ++j)
                    sa[i][j] = fmaf(av[i], bv[j], sa[i][j]);
        }

        // band mask
        #pragma unroll
        for (int i = 0; i < 4; ++i) {
            int t = t0 + ty * 4 + i;
            #pragma unroll
            for (int j = 0; j < 4; ++j) {
                int u = u0 + tx * 4 + j;
                int d = t - u;
                if (d > CTX || d < -CTX) sa[i][j] = -1e30f;
            }
        }

        // online softmax per row (reduce across the 16 tx lanes)
        float scale[4];
        #pragma unroll
        for (int i = 0; i < 4; ++i) {
            float rm = fmaxf(fmaxf(sa[i][0], sa[i][1]), fmaxf(sa[i][2], sa[i][3]));
            rm = fmaxf(rm, __shfl_xor(rm, 1));
            rm = fmaxf(rm, __shfl_xor(rm, 2));
            rm = fmaxf(rm, __shfl_xor(rm, 4));
            rm = fmaxf(rm, __shfl_xor(rm, 8));
            float mn = fmaxf(m[i], rm);
            scale[i] = __expf(m[i] - mn);
            m[i] = mn;
            float rs = 0.f;
            #pragma unroll
            for (int j = 0; j < 4; ++j) {
                float p = __expf(sa[i][j] - mn);
                sa[i][j] = p;
                rs += p;
            }
            rs += __shfl_xor(rs, 1);
            rs += __shfl_xor(rs, 2);
            rs += __shfl_xor(rs, 4);
            rs += __shfl_xor(rs, 8);
            l[i] = l[i] * scale[i] + rs;
        }

        // write P transposed
        #pragma unroll
        for (int i = 0; i < 4; ++i)
            #pragma unroll
            for (int j = 0; j < 4; ++j)
                Ps[tx * 4 + j][ty * 4 + i] = sa[i][j];

        // rescale running O
        #pragma unroll
        for (int i = 0; i < 4; ++i)
            #pragma unroll
            for (int j = 0; j < 4; ++j)
                o[i][j] *= scale[i];
        __syncthreads();

        // O[t][s] += sum_u Ps[u][t] * Vs[u][s]
        #pragma unroll
        for (int k = 0; k < 64; ++k) {
            float4 a4 = *(const float4*)&Ps[k][ty * 4];
            float4 b4 = *(const float4*)&Vs[k][tx * 4];
            float av[4] = {a4.x, a4.y, a4.z, a4.w};
            float bv[4] = {b4.x, b4.y, b4.z, b4.w};
            #pragma unroll
            for (int i = 0; i < 4; ++i)
                #pragma unroll
                for (int j = 0; j < 4; ++j)
                    o[i][j] = fmaf(av[i], bv[j], o[i][j]);
        }
    }

    // finalize: divide by l, write C[b][t][h][s]
    #pragma unroll
    for (int i = 0; i < 4; ++i) {
        float inv = 1.f / l[i];
        int t = t0 + ty * 4 + i;
        float4 v4 = make_float4(o[i][0] * inv, o[i][1] * inv,
                                o[i][2] * inv, o[i][3] * inv);
        *(float4*)(C + (((size_t)(b * TSEQ + t) * NH + h) * HS) + tx * 4) = v4;
    }
}

// ---------------------------------------------------------------------------
// Kernel 3: output projection. out[8192,512] = C[8192,512] @ WU[512,512]
// ---------------------------------------------------------------------------
__global__ __launch_bounds__(256) void out_proj_kernel(
    const float* __restrict__ Cmat,  // [8192, 512]
    const float* __restrict__ WU,    // [512, 512]
    float* __restrict__ out)         // [8192, 512]
{
    __shared__ float As[32][72];
    __shared__ float Bs[32][68];

    const int tid = threadIdx.x;
    const int tx = tid & 15, ty = tid >> 4;
    const int r0 = blockIdx.x * 64;
    const int c0 = blockIdx.y * 64;

    float acc[4][4] = {};

    for (int k0 = 0; k0 < DM; k0 += 32) {
        #pragma unroll
        for (int i = 0; i < 2; ++i) {
            int idx = tid + i * 256;
            int row = idx >> 3;
            int kk  = (idx & 7) * 4;
            float4 a = *(const float4*)(Cmat + (size_t)(r0 + row) * DM + k0 + kk);
            As[kk + 0][row] = a.x; As[kk + 1][row] = a.y;
            As[kk + 2][row] = a.z; As[kk + 3][row] = a.w;
        }
        #pragma unroll
        for (int i = 0; i < 2; ++i) {
            int idx = tid + i * 256;
            int kk = idx >> 4;
            int c  = (idx & 15) * 4;
            *(float4*)&Bs[kk][c] = *(const float4*)(WU + (size_t)(k0 + kk) * DM + c0 + c);
        }
        __syncthreads();

        #pragma unroll
        for (int k = 0; k < 32; ++k) {
            float4 a4 = *(const float4*)&As[k][ty * 4];
            float4 b4 = *(const float4*)&Bs[k][tx * 4];
            float av[4] = {a4.x, a4.y, a4.z, a4.w};
            float bv[4] = {b4.x, b4.y, b4.z, b4.w};
            #pragma unroll
            for (int i = 0; i < 4; ++i)
                #pragma unroll
                for (int j = 0; j < 4; ++j)
                    acc[i][j] = fmaf(av[i], bv[j], acc[i][j]);
        }
        __syncthreads();
    }

    #pragma unroll
    for (int i = 0; i < 4; ++i) {
        int r = r0 + ty * 4 + i;
        float4 v4 = make_float4(acc[i][0], acc[i][1], acc[i][2], acc[i][3]);
        *(float4*)(out + (size_t)r * DM + c0 + tx * 4) = v4;
    }
}

// ---------------------------------------------------------------------------
extern "C" void kernel_launch(void* const* d_in, const int* in_sizes, int n_in,
                              void* d_out, int out_size, void* d_ws, size_t ws_size,
                              hipStream_t stream) {
    const float* X  = (const float*)d_in[0];
    const float* WQ = (const float*)d_in[1];
    const float* WV = (const float*)d_in[2];
    const float* WU = (const float*)d_in[3];
    float* out = (float*)d_out;

    const size_t qv_elems = (size_t)BATCH * NH * TSEQ * HS;  // 4,194,304
    float* Q = (float*)d_ws;
    float* V = Q + qv_elems;
    float* C = V + qv_elems;

    qv_proj_kernel<<<dim3(128, 16), 256, 0, stream>>>(X, WQ, WV, Q, V);
    attn_kernel<<<dim3(BATCH * NH * (TSEQ / 64)), 256, 0, stream>>>(Q, V, C);
    out_proj_kernel<<<dim3(128, 8), 256, 0, stream>>>(C, WU, out);
}

// Round 2
// 185.380 us; speedup vs baseline: 2.1617x; 2.1617x over previous
//
#include <hip/hip_runtime.h>

#define TSEQ 4096
#define DM 512
#define NH 8
#define HS 64
#define CTX 256

typedef __attribute__((ext_vector_type(8))) short bf16x8;
typedef __attribute__((ext_vector_type(4))) float f32x4;

__device__ __forceinline__ unsigned short f2bf(float x) {
    unsigned u = __float_as_uint(x);
    unsigned r = (u + 0x7fffu + ((u >> 16) & 1u)) >> 16;
    return (unsigned short)r;
}
__device__ __forceinline__ float bf2f(unsigned short b) {
    return __uint_as_float(((unsigned)b) << 16);
}
// split 8 consecutive floats into hi/lo bf16 fragments
__device__ __forceinline__ void split8(const float* v, bf16x8& h, bf16x8& l) {
    #pragma unroll
    for (int i = 0; i < 8; ++i) {
        unsigned short hb = f2bf(v[i]);
        float hf = bf2f(hb);
        unsigned short lb = f2bf(v[i] - hf);
        h[i] = (short)hb;
        l[i] = (short)lb;
    }
}

#define MFMA(a, b, c) __builtin_amdgcn_mfma_f32_16x16x32_bf16((a), (b), (c), 0, 0, 0)

// ---------------------------------------------------------------------------
// Generic split-bf16 MFMA GEMM: 128x64 tile, K=512, BK=64.
// mode 0: qv projection (y<8 -> Q head y, else V head y-8), out [bh][t][64]
// mode 1: out projection, W=WU col block y, out [8192][512]
// ---------------------------------------------------------------------------
__global__ __launch_bounds__(256) void gemm_mfma(
    const float* __restrict__ A,    // [8192][512]
    const float* __restrict__ W0,
    const float* __restrict__ W1,
    float* __restrict__ O0,
    float* __restrict__ O1,
    int mode)
{
    __shared__ unsigned short Ah[128][72], Al[128][72];
    __shared__ unsigned short Bh[64][72],  Bl[64][72];

    const int tid = threadIdx.x;
    const int w = tid >> 6, lane = tid & 63;
    const int lg = lane >> 4, ln = lane & 15;
    const int r0 = blockIdx.x * 128;
    const int y = blockIdx.y;

    const float* Wp;
    int ldw;
    if (mode == 0) {
        Wp = ((y < 8) ? W0 : W1) + (size_t)(y & 7) * DM * HS;
        ldw = HS;
    } else {
        Wp = W0 + (size_t)y * 64;
        ldw = DM;
    }

    f32x4 acc[2][4];
    #pragma unroll
    for (int i = 0; i < 2; ++i)
        #pragma unroll
        for (int j = 0; j < 4; ++j)
            acc[i][j] = (f32x4){0.f, 0.f, 0.f, 0.f};

    for (int kt = 0; kt < 8; ++kt) {
        const int k0 = kt * 64;
        // stage A [128 rows][64 k] -> hi/lo, row-major k-contiguous
        #pragma unroll
        for (int i2 = 0; i2 < 4; ++i2) {
            int unit = tid + i2 * 256;            // 0..1023
            int row = unit >> 3, kc = unit & 7;
            const float* src = A + (size_t)(r0 + row) * DM + k0 + kc * 8;
            float4 p0 = *(const float4*)src;
            float4 p1 = *(const float4*)(src + 4);
            float v[8] = {p0.x, p0.y, p0.z, p0.w, p1.x, p1.y, p1.z, p1.w};
            bf16x8 h, l;
            split8(v, h, l);
            *(bf16x8*)&Ah[row][kc * 8] = h;
            *(bf16x8*)&Al[row][kc * 8] = l;
        }
        // stage B transposed: W[k][n] -> B*[n][k]
        #pragma unroll
        for (int i2 = 0; i2 < 4; ++i2) {
            int unit = tid + i2 * 256;
            int k = unit >> 4, ng = unit & 15;
            const float* src = Wp + (size_t)(k0 + k) * ldw + ng * 4;
            float4 wv = *(const float4*)src;
            float vv[4] = {wv.x, wv.y, wv.z, wv.w};
            #pragma unroll
            for (int e = 0; e < 4; ++e) {
                unsigned short hb = f2bf(vv[e]);
                Bh[ng * 4 + e][k] = hb;
                Bl[ng * 4 + e][k] = f2bf(vv[e] - bf2f(hb));
            }
        }
        __syncthreads();

        #pragma unroll
        for (int kk = 0; kk < 2; ++kk) {
            bf16x8 ah[2], al[2], bh2[4], bl2[4];
            #pragma unroll
            for (int ti = 0; ti < 2; ++ti) {
                ah[ti] = *(const bf16x8*)&Ah[w * 32 + ti * 16 + ln][kk * 32 + lg * 8];
                al[ti] = *(const bf16x8*)&Al[w * 32 + ti * 16 + ln][kk * 32 + lg * 8];
            }
            #pragma unroll
            for (int nj = 0; nj < 4; ++nj) {
                bh2[nj] = *(const bf16x8*)&Bh[nj * 16 + ln][kk * 32 + lg * 8];
                bl2[nj] = *(const bf16x8*)&Bl[nj * 16 + ln][kk * 32 + lg * 8];
            }
            #pragma unroll
            for (int ti = 0; ti < 2; ++ti)
                #pragma unroll
                for (int nj = 0; nj < 4; ++nj) {
                    acc[ti][nj] = MFMA(ah[ti], bh2[nj], acc[ti][nj]);
                    acc[ti][nj] = MFMA(ah[ti], bl2[nj], acc[ti][nj]);
                    acc[ti][nj] = MFMA(al[ti], bh2[nj], acc[ti][nj]);
                }
        }
        __syncthreads();
    }

    // epilogue: D row = (lane>>4)*4 + r, col = lane&15
    #pragma unroll
    for (int ti = 0; ti < 2; ++ti)
        #pragma unroll
        for (int nj = 0; nj < 4; ++nj)
            #pragma unroll
            for (int r = 0; r < 4; ++r) {
                float val = acc[ti][nj][r];
                int t = r0 + w * 32 + ti * 16 + lg * 4 + r;
                int n = nj * 16 + ln;
                if (mode == 0) {
                    int b = t >> 12, tt = t & (TSEQ - 1);
                    float* Op = (y < 8) ? O0 : O1;
                    Op[((size_t)(b * NH + (y & 7)) * TSEQ + tt) * HS + n] = val;
                } else {
                    O0[(size_t)t * DM + y * 64 + n] = val;
                }
            }
}

// ---------------------------------------------------------------------------
// Banded flash attention, split-bf16 MFMA.
// Block: 128 t-rows of one (b,h); 4 waves x (32t x 64u).
// ---------------------------------------------------------------------------
__global__ __launch_bounds__(256) void attn_mfma(
    const float* __restrict__ Q,   // [bh][4096][64]
    const float* __restrict__ V,   // [bh][4096][64]
    float* __restrict__ C)         // [8192][512]  ([b][t][h*64+s])
{
    __shared__ unsigned short Vn_h[64][72], Vn_l[64][72];   // [u][s]
    __shared__ unsigned short Vt_h[64][72], Vt_l[64][72];   // [s][u]
    __shared__ unsigned short Ps_h[128][72], Ps_l[128][72]; // [t][u]

    const int tid = threadIdx.x;
    const int w = tid >> 6, lane = tid & 63;
    const int lg = lane >> 4, ln = lane & 15;
    const int ttile = blockIdx.x & 31;
    const int bh = blockIdx.x >> 5;
    const int t0 = ttile * 128;
    const float* Qp = Q + (size_t)bh * TSEQ * HS;
    const float* Vp = V + (size_t)bh * TSEQ * HS;

    // register-resident Q fragments (prescaled by 1/sqrt(64))
    bf16x8 qh[2][2], ql[2][2];
    #pragma unroll
    for (int ti = 0; ti < 2; ++ti)
        #pragma unroll
        for (int kk = 0; kk < 2; ++kk) {
            int trow = t0 + w * 32 + ti * 16 + ln;
            const float* src = Qp + (size_t)trow * HS + kk * 32 + lg * 8;
            float4 p0 = *(const float4*)src;
            float4 p1 = *(const float4*)(src + 4);
            float v[8] = {p0.x * 0.125f, p0.y * 0.125f, p0.z * 0.125f, p0.w * 0.125f,
                          p1.x * 0.125f, p1.y * 0.125f, p1.z * 0.125f, p1.w * 0.125f};
            split8(v, qh[ti][kk], ql[ti][kk]);
        }

    f32x4 o[2][4];
    float m[2][4], lsum[2][4];
    #pragma unroll
    for (int ti = 0; ti < 2; ++ti)
        #pragma unroll
        for (int j = 0; j < 4; ++j) {
            o[ti][j] = (f32x4){0.f, 0.f, 0.f, 0.f};
            m[ti][j] = -1e30f;
            lsum[ti][j] = 0.f;
        }

    int u_lo = t0 - CTX; if (u_lo < 0) u_lo = 0;
    int u_hi = t0 + 128 + CTX; if (u_hi > TSEQ) u_hi = TSEQ;

    for (int u0 = u_lo; u0 < u_hi; u0 += 64) {
        __syncthreads();   // previous chunk's LDS readers done
        // stage V chunk: natural [u][s] and transposed [s][u], hi/lo
        #pragma unroll
        for (int i2 = 0; i2 < 2; ++i2) {
            int unit = tid + i2 * 256;           // 0..511
            int u = unit >> 3, sc = unit & 7;
            const float* src = Vp + (size_t)(u0 + u) * HS + sc * 8;
            float4 p0 = *(const float4*)src;
            float4 p1 = *(const float4*)(src + 4);
            float v[8] = {p0.x, p0.y, p0.z, p0.w, p1.x, p1.y, p1.z, p1.w};
            bf16x8 h, l;
            split8(v, h, l);
            *(bf16x8*)&Vn_h[u][sc * 8] = h;
            *(bf16x8*)&Vn_l[u][sc * 8] = l;
            #pragma unroll
            for (int e = 0; e < 8; ++e) {
                Vt_h[sc * 8 + e][u] = (unsigned short)h[e];
                Vt_l[sc * 8 + e][u] = (unsigned short)l[e];
            }
        }
        __syncthreads();

        // scores: S[t][u] = sum_s Q[t][s] V[u][s]
        f32x4 s[2][4];
        #pragma unroll
        for (int ti = 0; ti < 2; ++ti)
            #pragma unroll
            for (int j = 0; j < 4; ++j)
                s[ti][j] = (f32x4){0.f, 0.f, 0.f, 0.f};

        #pragma unroll
        for (int kk = 0; kk < 2; ++kk) {
            bf16x8 vh[4], vl[4];
            #pragma unroll
            for (int uj = 0; uj < 4; ++uj) {
                vh[uj] = *(const bf16x8*)&Vn_h[uj * 16 + ln][kk * 32 + lg * 8];
                vl[uj] = *(const bf16x8*)&Vn_l[uj * 16 + ln][kk * 32 + lg * 8];
            }
            #pragma unroll
            for (int ti = 0; ti < 2; ++ti)
                #pragma unroll
                for (int uj = 0; uj < 4; ++uj) {
                    s[ti][uj] = MFMA(qh[ti][kk], vh[uj], s[ti][uj]);
                    s[ti][uj] = MFMA(qh[ti][kk], vl[uj], s[ti][uj]);
                    s[ti][uj] = MFMA(ql[ti][kk], vh[uj], s[ti][uj]);
                }
        }

        // band mask (only first/last chunks actually need it)
        bool needmask = ((t0 + 127 - u0) > CTX) || ((u0 + 63 - t0) > CTX);
        if (needmask) {
            #pragma unroll
            for (int ti = 0; ti < 2; ++ti)
                #pragma unroll
                for (int uj = 0; uj < 4; ++uj)
                    #pragma unroll
                    for (int r = 0; r < 4; ++r) {
                        int t = t0 + w * 32 + ti * 16 + lg * 4 + r;
                        int u = u0 + uj * 16 + ln;
                        int d = t - u; if (d < 0) d = -d;
                        if (d > CTX) s[ti][uj][r] = -1e30f;
                    }
        }

        // online softmax per row (t fixed per (ti, r) within lg group)
        float scl[2][4];
        #pragma unroll
        for (int ti = 0; ti < 2; ++ti)
            #pragma unroll
            for (int r = 0; r < 4; ++r) {
                float rm = fmaxf(fmaxf(s[ti][0][r], s[ti][1][r]),
                                 fmaxf(s[ti][2][r], s[ti][3][r]));
                rm = fmaxf(rm, __shfl_xor(rm, 1));
                rm = fmaxf(rm, __shfl_xor(rm, 2));
                rm = fmaxf(rm, __shfl_xor(rm, 4));
                rm = fmaxf(rm, __shfl_xor(rm, 8));
                float mn = fmaxf(m[ti][r], rm);
                float sc = __expf(m[ti][r] - mn);
                m[ti][r] = mn;
                scl[ti][r] = sc;
                float rs = 0.f;
                #pragma unroll
                for (int uj = 0; uj < 4; ++uj) {
                    float p = __expf(s[ti][uj][r] - mn);
                    s[ti][uj][r] = p;
                    rs += p;
                }
                rs += __shfl_xor(rs, 1);
                rs += __shfl_xor(rs, 2);
                rs += __shfl_xor(rs, 4);
                rs += __shfl_xor(rs, 8);
                lsum[ti][r] = lsum[ti][r] * sc + rs;
            }

        // write P (hi/lo) to per-wave LDS strip; same-wave consumption, no barrier
        #pragma unroll
        for (int ti = 0; ti < 2; ++ti)
            #pragma unroll
            for (int uj = 0; uj < 4; ++uj)
                #pragma unroll
                for (int r = 0; r < 4; ++r) {
                    float p = s[ti][uj][r];
                    int t = w * 32 + ti * 16 + lg * 4 + r;
                    int u = uj * 16 + ln;
                    unsigned short hb = f2bf(p);
                    Ps_h[t][u] = hb;
                    Ps_l[t][u] = f2bf(p - bf2f(hb));
                }

        // rescale running O
        #pragma unroll
        for (int ti = 0; ti < 2; ++ti)
            #pragma unroll
            for (int sj = 0; sj < 4; ++sj)
                #pragma unroll
                for (int r = 0; r < 4; ++r)
                    o[ti][sj][r] *= scl[ti][r];

        // PV: O[t][s] += sum_u P[t][u] V[u][s]
        #pragma unroll
        for (int kk = 0; kk < 2; ++kk) {
            bf16x8 ph[2], pl[2], vth[4], vtl[4];
            #pragma unroll
            for (int ti = 0; ti < 2; ++ti) {
                ph[ti] = *(const bf16x8*)&Ps_h[w * 32 + ti * 16 + ln][kk * 32 + lg * 8];
                pl[ti] = *(const bf16x8*)&Ps_l[w * 32 + ti * 16 + ln][kk * 32 + lg * 8];
            }
            #pragma unroll
            for (int sj = 0; sj < 4; ++sj) {
                vth[sj] = *(const bf16x8*)&Vt_h[sj * 16 + ln][kk * 32 + lg * 8];
                vtl[sj] = *(const bf16x8*)&Vt_l[sj * 16 + ln][kk * 32 + lg * 8];
            }
            #pragma unroll
            for (int ti = 0; ti < 2; ++ti)
                #pragma unroll
                for (int sj = 0; sj < 4; ++sj) {
                    o[ti][sj] = MFMA(ph[ti], vth[sj], o[ti][sj]);
                    o[ti][sj] = MFMA(ph[ti], vtl[sj], o[ti][sj]);
                    o[ti][sj] = MFMA(pl[ti], vth[sj], o[ti][sj]);
                }
        }
    }

    // epilogue
    const int b = bh >> 3, h = bh & 7;
    #pragma unroll
    for (int ti = 0; ti < 2; ++ti)
        #pragma unroll
        for (int r = 0; r < 4; ++r) {
            float inv = 1.f / lsum[ti][r];
            int t = t0 + w * 32 + ti * 16 + lg * 4 + r;
            #pragma unroll
            for (int sj = 0; sj < 4; ++sj) {
                int ss = sj * 16 + ln;
                C[((size_t)(b * TSEQ + t)) * DM + h * HS + ss] = o[ti][sj][r] * inv;
            }
        }
}

// ---------------------------------------------------------------------------
extern "C" void kernel_launch(void* const* d_in, const int* in_sizes, int n_in,
                              void* d_out, int out_size, void* d_ws, size_t ws_size,
                              hipStream_t stream) {
    const float* X  = (const float*)d_in[0];
    const float* WQ = (const float*)d_in[1];
    const float* WV = (const float*)d_in[2];
    const float* WU = (const float*)d_in[3];
    float* out = (float*)d_out;

    const size_t qv_elems = (size_t)2 * NH * TSEQ * HS;  // 4,194,304
    float* Q = (float*)d_ws;
    float* V = Q + qv_elems;
    float* C = V + qv_elems;

    gemm_mfma<<<dim3(64, 16), 256, 0, stream>>>(X, WQ, WV, Q, V, 0);
    attn_mfma<<<dim3(2 * NH * (TSEQ / 128)), 256, 0, stream>>>(Q, V, C);
    gemm_mfma<<<dim3(64, 8), 256, 0, stream>>>(C, WU, nullptr, out, nullptr, 1);
}

// Round 3
// 153.182 us; speedup vs baseline: 2.6161x; 1.2102x over previous
//
#include <hip/hip_runtime.h>

#define TSEQ 4096
#define DM 512
#define NH 8
#define HS 64
#define CTX 256

typedef __attribute__((ext_vector_type(8))) short bf16x8;
typedef __attribute__((ext_vector_type(4))) float f32x4;
typedef unsigned short u16;

__device__ __forceinline__ u16 f2bf(float x) {
    unsigned u = __float_as_uint(x);
    unsigned r = (u + 0x7fffu + ((u >> 16) & 1u)) >> 16;
    return (u16)r;
}
__device__ __forceinline__ float bf2f(u16 b) {
    return __uint_as_float(((unsigned)b) << 16);
}
__device__ __forceinline__ void split8(const float* v, bf16x8& h, bf16x8& l) {
    #pragma unroll
    for (int i = 0; i < 8; ++i) {
        u16 hb = f2bf(v[i]);
        float hf = bf2f(hb);
        u16 lb = f2bf(v[i] - hf);
        h[i] = (short)hb;
        l[i] = (short)lb;
    }
}

#define MFMA(a, b, c) __builtin_amdgcn_mfma_f32_16x16x32_bf16((a), (b), (c), 0, 0, 0)

// ---------------------------------------------------------------------------
// Pre-split X: [8192*512] f32 -> Xh, Xl bf16
// ---------------------------------------------------------------------------
__global__ __launch_bounds__(256) void presplit_x(
    const float* __restrict__ X, u16* __restrict__ Xh, u16* __restrict__ Xl)
{
    size_t idx = ((size_t)blockIdx.x * 256 + threadIdx.x) * 8;
    float4 p0 = *(const float4*)(X + idx);
    float4 p1 = *(const float4*)(X + idx + 4);
    float v[8] = {p0.x, p0.y, p0.z, p0.w, p1.x, p1.y, p1.z, p1.w};
    bf16x8 h, l;
    split8(v, h, l);
    *(bf16x8*)(Xh + idx) = h;
    *(bf16x8*)(Xl + idx) = l;
}

// ---------------------------------------------------------------------------
// Pre-split + transpose weights.
// WQ[h][d][s] -> WQt[h][s][d]; WV same; WU[c][d] -> WUt[d][c]. hi/lo bf16.
// ---------------------------------------------------------------------------
__global__ __launch_bounds__(256) void presplit_w(
    const float* __restrict__ WQ, const float* __restrict__ WV,
    const float* __restrict__ WU,
    u16* __restrict__ WQt_h, u16* __restrict__ WQt_l,
    u16* __restrict__ WVt_h, u16* __restrict__ WVt_l,
    u16* __restrict__ WUt_h, u16* __restrict__ WUt_l)
{
    int gidx = blockIdx.x * 256 + threadIdx.x;   // 0 .. 786431
    int a = gidx >> 18;                          // 0: WQ, 1: WV, 2: WU
    int r = gidx & 262143;
    float val;
    u16 *dh, *dl;
    int dst;
    if (a < 2) {
        int h = r >> 15, s = (r >> 9) & 63, d = r & 511;
        const float* W = (a == 0) ? WQ : WV;
        val = W[h * 32768 + d * 64 + s];
        dst = h * 32768 + s * 512 + d;
        dh = (a == 0) ? WQt_h : WVt_h;
        dl = (a == 0) ? WQt_l : WVt_l;
    } else {
        int n = r >> 9, k = r & 511;
        val = WU[k * 512 + n];
        dst = n * 512 + k;
        dh = WUt_h; dl = WUt_l;
    }
    u16 hb = f2bf(val);
    dh[dst] = hb;
    dl[dst] = f2bf(val - bf2f(hb));
}

// ---------------------------------------------------------------------------
// Split-bf16 MFMA GEMM, pre-split inputs. 128x64 tile, K=512, BK=64.
// mode 0: QV projection. A=Xh/Xl. y<8: B=WQt head y, out Qh/Ql (prescaled
//         1/8); y>=8: B=WVt head y-8, out Vh/Vl.  Out layout [bh][t][64].
// mode 1: out projection. A=Ch/Cl, B=WUt rows y*64.., out f32 [8192][512].
// ---------------------------------------------------------------------------
__global__ __launch_bounds__(256) void gemm_mfma(
    const u16* __restrict__ Ah_g, const u16* __restrict__ Al_g,
    const u16* __restrict__ B0h, const u16* __restrict__ B0l,
    const u16* __restrict__ B1h, const u16* __restrict__ B1l,
    u16* __restrict__ O0h, u16* __restrict__ O0l,
    u16* __restrict__ O1h, u16* __restrict__ O1l,
    float* __restrict__ Of,
    int mode)
{
    __shared__ u16 Ah[128][72], Al[128][72];
    __shared__ u16 Bh[64][72],  Bl[64][72];

    const int tid = threadIdx.x;
    const int w = tid >> 6, lane = tid & 63;
    const int lg = lane >> 4, ln = lane & 15;
    const int r0 = blockIdx.x * 128;
    const int y = blockIdx.y;

    const u16 *Bsh, *Bsl;
    if (mode == 0) {
        if (y < 8) { Bsh = B0h + (size_t)y * 32768; Bsl = B0l + (size_t)y * 32768; }
        else       { Bsh = B1h + (size_t)(y - 8) * 32768; Bsl = B1l + (size_t)(y - 8) * 32768; }
    } else {
        Bsh = B0h + (size_t)y * 64 * 512;
        Bsl = B0l + (size_t)y * 64 * 512;
    }

    f32x4 acc[2][4];
    #pragma unroll
    for (int i = 0; i < 2; ++i)
        #pragma unroll
        for (int j = 0; j < 4; ++j)
            acc[i][j] = (f32x4){0.f, 0.f, 0.f, 0.f};

    for (int kt = 0; kt < 8; ++kt) {
        const int k0 = kt * 64;
        // A tile: 128 rows x 64 k, pure u16 b128 copies
        #pragma unroll
        for (int i2 = 0; i2 < 4; ++i2) {
            int unit = tid + i2 * 256;            // 0..1023
            int row = unit >> 3, kc = unit & 7;
            size_t off = (size_t)(r0 + row) * DM + k0 + kc * 8;
            *(bf16x8*)&Ah[row][kc * 8] = *(const bf16x8*)(Ah_g + off);
            *(bf16x8*)&Al[row][kc * 8] = *(const bf16x8*)(Al_g + off);
        }
        // B tile: 64 rows x 64 k
        #pragma unroll
        for (int i2 = 0; i2 < 2; ++i2) {
            int unit = tid + i2 * 256;            // 0..511
            int n = unit >> 3, kc = unit & 7;
            size_t off = (size_t)n * 512 + k0 + kc * 8;
            *(bf16x8*)&Bh[n][kc * 8] = *(const bf16x8*)(Bsh + off);
            *(bf16x8*)&Bl[n][kc * 8] = *(const bf16x8*)(Bsl + off);
        }
        __syncthreads();

        #pragma unroll
        for (int kk = 0; kk < 2; ++kk) {
            bf16x8 ah[2], al[2], bh2[4], bl2[4];
            #pragma unroll
            for (int ti = 0; ti < 2; ++ti) {
                ah[ti] = *(const bf16x8*)&Ah[w * 32 + ti * 16 + ln][kk * 32 + lg * 8];
                al[ti] = *(const bf16x8*)&Al[w * 32 + ti * 16 + ln][kk * 32 + lg * 8];
            }
            #pragma unroll
            for (int nj = 0; nj < 4; ++nj) {
                bh2[nj] = *(const bf16x8*)&Bh[nj * 16 + ln][kk * 32 + lg * 8];
                bl2[nj] = *(const bf16x8*)&Bl[nj * 16 + ln][kk * 32 + lg * 8];
            }
            #pragma unroll
            for (int ti = 0; ti < 2; ++ti)
                #pragma unroll
                for (int nj = 0; nj < 4; ++nj) {
                    acc[ti][nj] = MFMA(ah[ti], bh2[nj], acc[ti][nj]);
                    acc[ti][nj] = MFMA(ah[ti], bl2[nj], acc[ti][nj]);
                    acc[ti][nj] = MFMA(al[ti], bh2[nj], acc[ti][nj]);
                }
        }
        __syncthreads();
    }

    const float qscale = (mode == 0 && y < 8) ? 0.125f : 1.0f;
    #pragma unroll
    for (int ti = 0; ti < 2; ++ti)
        #pragma unroll
        for (int nj = 0; nj < 4; ++nj)
            #pragma unroll
            for (int r = 0; r < 4; ++r) {
                float val = acc[ti][nj][r] * qscale;
                int t = r0 + w * 32 + ti * 16 + lg * 4 + r;
                int n = nj * 16 + ln;
                if (mode == 0) {
                    int bh = (t >> 12) * NH + (y & 7);
                    size_t off = ((size_t)bh * TSEQ + (t & (TSEQ - 1))) * HS + n;
                    u16 hb = f2bf(val);
                    u16 lb = f2bf(val - bf2f(hb));
                    if (y < 8) { O0h[off] = hb; O0l[off] = lb; }
                    else       { O1h[off] = hb; O1l[off] = lb; }
                } else {
                    Of[(size_t)t * DM + y * 64 + n] = val;
                }
            }
}

// ---------------------------------------------------------------------------
// Banded flash attention, split-bf16 MFMA, pre-split Q/V inputs.
// Block: 128 t-rows of one (b,h); 4 waves x (32t x 64u). Out: split bf16 C.
// ---------------------------------------------------------------------------
__global__ __launch_bounds__(256) void attn_mfma(
    const u16* __restrict__ Qh_g, const u16* __restrict__ Ql_g,
    const u16* __restrict__ Vh_g, const u16* __restrict__ Vl_g,
    u16* __restrict__ Ch, u16* __restrict__ Cl)
{
    __shared__ u16 Vn_h[64][72], Vn_l[64][72];   // [u][s]
    __shared__ u16 Vt_h[64][72], Vt_l[64][72];   // [s][u]
    __shared__ unsigned Ps[128][76];             // [t][u] packed hi|lo<<16

    const int tid = threadIdx.x;
    const int w = tid >> 6, lane = tid & 63;
    const int lg = lane >> 4, ln = lane & 15;
    const int ttile = blockIdx.x & 31;
    const int bh = blockIdx.x >> 5;
    const int t0 = ttile * 128;
    const u16* Qph = Qh_g + (size_t)bh * TSEQ * HS;
    const u16* Qpl = Ql_g + (size_t)bh * TSEQ * HS;
    const u16* Vph = Vh_g + (size_t)bh * TSEQ * HS;
    const u16* Vpl = Vl_g + (size_t)bh * TSEQ * HS;

    // register-resident Q fragments (already prescaled by 1/8 in projection)
    bf16x8 qh[2][2], ql[2][2];
    #pragma unroll
    for (int ti = 0; ti < 2; ++ti)
        #pragma unroll
        for (int kk = 0; kk < 2; ++kk) {
            int trow = t0 + w * 32 + ti * 16 + ln;
            size_t off = (size_t)trow * HS + kk * 32 + lg * 8;
            qh[ti][kk] = *(const bf16x8*)(Qph + off);
            ql[ti][kk] = *(const bf16x8*)(Qpl + off);
        }

    f32x4 o[2][4];
    float m[2][4], lsum[2][4];
    #pragma unroll
    for (int ti = 0; ti < 2; ++ti)
        #pragma unroll
        for (int j = 0; j < 4; ++j) {
            o[ti][j] = (f32x4){0.f, 0.f, 0.f, 0.f};
            m[ti][j] = -1e30f;
            lsum[ti][j] = 0.f;
        }

    int u_lo = t0 - CTX; if (u_lo < 0) u_lo = 0;
    int u_hi = t0 + 128 + CTX; if (u_hi > TSEQ) u_hi = TSEQ;

    for (int u0 = u_lo; u0 < u_hi; u0 += 64) {
        __syncthreads();
        // stage V chunk: natural [u][s] vectorized + transposed [s][u] scalar
        #pragma unroll
        for (int i2 = 0; i2 < 2; ++i2) {
            int unit = tid + i2 * 256;           // 0..511
            int u = unit >> 3, sc = unit & 7;
            size_t off = (size_t)(u0 + u) * HS + sc * 8;
            bf16x8 h = *(const bf16x8*)(Vph + off);
            bf16x8 l = *(const bf16x8*)(Vpl + off);
            *(bf16x8*)&Vn_h[u][sc * 8] = h;
            *(bf16x8*)&Vn_l[u][sc * 8] = l;
            #pragma unroll
            for (int e = 0; e < 8; ++e) {
                Vt_h[sc * 8 + e][u] = (u16)h[e];
                Vt_l[sc * 8 + e][u] = (u16)l[e];
            }
        }
        __syncthreads();

        // scores: S[t][u] = sum_s Q[t][s] V[u][s]
        f32x4 s[2][4];
        #pragma unroll
        for (int ti = 0; ti < 2; ++ti)
            #pragma unroll
            for (int j = 0; j < 4; ++j)
                s[ti][j] = (f32x4){0.f, 0.f, 0.f, 0.f};

        #pragma unroll
        for (int kk = 0; kk < 2; ++kk) {
            bf16x8 vh[4], vl[4];
            #pragma unroll
            for (int uj = 0; uj < 4; ++uj) {
                vh[uj] = *(const bf16x8*)&Vn_h[uj * 16 + ln][kk * 32 + lg * 8];
                vl[uj] = *(const bf16x8*)&Vn_l[uj * 16 + ln][kk * 32 + lg * 8];
            }
            #pragma unroll
            for (int ti = 0; ti < 2; ++ti)
                #pragma unroll
                for (int uj = 0; uj < 4; ++uj) {
                    s[ti][uj] = MFMA(qh[ti][kk], vh[uj], s[ti][uj]);
                    s[ti][uj] = MFMA(qh[ti][kk], vl[uj], s[ti][uj]);
                    s[ti][uj] = MFMA(ql[ti][kk], vh[uj], s[ti][uj]);
                }
        }

        // band mask
        bool needmask = ((t0 + 127 - u0) > CTX) || ((u0 + 63 - t0) > CTX);
        if (needmask) {
            #pragma unroll
            for (int ti = 0; ti < 2; ++ti)
                #pragma unroll
                for (int uj = 0; uj < 4; ++uj)
                    #pragma unroll
                    for (int r = 0; r < 4; ++r) {
                        int t = t0 + w * 32 + ti * 16 + lg * 4 + r;
                        int u = u0 + uj * 16 + ln;
                        int d = t - u; if (d < 0) d = -d;
                        if (d > CTX) s[ti][uj][r] = -1e30f;
                    }
        }

        // online softmax per row
        float scl[2][4];
        #pragma unroll
        for (int ti = 0; ti < 2; ++ti)
            #pragma unroll
            for (int r = 0; r < 4; ++r) {
                float rm = fmaxf(fmaxf(s[ti][0][r], s[ti][1][r]),
                                 fmaxf(s[ti][2][r], s[ti][3][r]));
                rm = fmaxf(rm, __shfl_xor(rm, 1));
                rm = fmaxf(rm, __shfl_xor(rm, 2));
                rm = fmaxf(rm, __shfl_xor(rm, 4));
                rm = fmaxf(rm, __shfl_xor(rm, 8));
                float mn = fmaxf(m[ti][r], rm);
                float sc = __expf(m[ti][r] - mn);
                m[ti][r] = mn;
                scl[ti][r] = sc;
                float rs = 0.f;
                #pragma unroll
                for (int uj = 0; uj < 4; ++uj) {
                    float p = __expf(s[ti][uj][r] - mn);
                    s[ti][uj][r] = p;
                    rs += p;
                }
                rs += __shfl_xor(rs, 1);
                rs += __shfl_xor(rs, 2);
                rs += __shfl_xor(rs, 4);
                rs += __shfl_xor(rs, 8);
                lsum[ti][r] = lsum[ti][r] * sc + rs;
            }

        // write P packed (hi | lo<<16); per-wave strip, same-wave consumption
        #pragma unroll
        for (int ti = 0; ti < 2; ++ti)
            #pragma unroll
            for (int uj = 0; uj < 4; ++uj)
                #pragma unroll
                for (int r = 0; r < 4; ++r) {
                    float p = s[ti][uj][r];
                    u16 hb = f2bf(p);
                    u16 lb = f2bf(p - bf2f(hb));
                    int t = w * 32 + ti * 16 + lg * 4 + r;
                    int u = uj * 16 + ln;
                    Ps[t][u] = (unsigned)hb | ((unsigned)lb << 16);
                }

        // rescale running O
        #pragma unroll
        for (int ti = 0; ti < 2; ++ti)
            #pragma unroll
            for (int sj = 0; sj < 4; ++sj)
                #pragma unroll
                for (int r = 0; r < 4; ++r)
                    o[ti][sj][r] *= scl[ti][r];

        // PV: O[t][s] += sum_u P[t][u] V[u][s]
        #pragma unroll
        for (int kk = 0; kk < 2; ++kk) {
            bf16x8 ph[2], pl[2], vth[4], vtl[4];
            #pragma unroll
            for (int ti = 0; ti < 2; ++ti) {
                const unsigned* prow = &Ps[w * 32 + ti * 16 + ln][kk * 32 + lg * 8];
                uint4 q0 = *(const uint4*)prow;
                uint4 q1 = *(const uint4*)(prow + 4);
                union { unsigned u[4]; bf16x8 v; } H, L;
                H.u[0] = __builtin_amdgcn_perm(q0.y, q0.x, 0x05040100u);
                H.u[1] = __builtin_amdgcn_perm(q0.w, q0.z, 0x05040100u);
                H.u[2] = __builtin_amdgcn_perm(q1.y, q1.x, 0x05040100u);
                H.u[3] = __builtin_amdgcn_perm(q1.w, q1.z, 0x05040100u);
                L.u[0] = __builtin_amdgcn_perm(q0.y, q0.x, 0x07060302u);
                L.u[1] = __builtin_amdgcn_perm(q0.w, q0.z, 0x07060302u);
                L.u[2] = __builtin_amdgcn_perm(q1.y, q1.x, 0x07060302u);
                L.u[3] = __builtin_amdgcn_perm(q1.w, q1.z, 0x07060302u);
                ph[ti] = H.v;
                pl[ti] = L.v;
            }
            #pragma unroll
            for (int sj = 0; sj < 4; ++sj) {
                vth[sj] = *(const bf16x8*)&Vt_h[sj * 16 + ln][kk * 32 + lg * 8];
                vtl[sj] = *(const bf16x8*)&Vt_l[sj * 16 + ln][kk * 32 + lg * 8];
            }
            #pragma unroll
            for (int ti = 0; ti < 2; ++ti)
                #pragma unroll
                for (int sj = 0; sj < 4; ++sj) {
                    o[ti][sj] = MFMA(ph[ti], vth[sj], o[ti][sj]);
                    o[ti][sj] = MFMA(ph[ti], vtl[sj], o[ti][sj]);
                    o[ti][sj] = MFMA(pl[ti], vth[sj], o[ti][sj]);
                }
        }
    }

    // epilogue: C as split bf16, layout [b][t][h*64+s]
    const int b = bh >> 3, h = bh & 7;
    #pragma unroll
    for (int ti = 0; ti < 2; ++ti)
        #pragma unroll
        for (int r = 0; r < 4; ++r) {
            float inv = 1.f / lsum[ti][r];
            int t = t0 + w * 32 + ti * 16 + lg * 4 + r;
            #pragma unroll
            for (int sj = 0; sj < 4; ++sj) {
                int ss = sj * 16 + ln;
                float val = o[ti][sj][r] * inv;
                size_t off = ((size_t)(b * TSEQ + t)) * DM + h * HS + ss;
                u16 hb = f2bf(val);
                Ch[off] = hb;
                Cl[off] = f2bf(val - bf2f(hb));
            }
        }
}

// ---------------------------------------------------------------------------
extern "C" void kernel_launch(void* const* d_in, const int* in_sizes, int n_in,
                              void* d_out, int out_size, void* d_ws, size_t ws_size,
                              hipStream_t stream) {
    const float* X  = (const float*)d_in[0];
    const float* WQ = (const float*)d_in[1];
    const float* WV = (const float*)d_in[2];
    const float* WU = (const float*)d_in[3];
    float* out = (float*)d_out;

    const size_t SZ = 8388608;   // 8 MB region
    char* ws = (char*)d_ws;
    u16* Xh = (u16*)(ws);             // later reused as Ch
    u16* Xl = (u16*)(ws + SZ);        // later reused as Cl
    u16* Qh = (u16*)(ws + 2 * SZ);
    u16* Ql = (u16*)(ws + 3 * SZ);
    u16* Vh = (u16*)(ws + 4 * SZ);
    u16* Vl = (u16*)(ws + 5 * SZ);
    char* wsw = ws + 6 * SZ;
    u16* WQt_h = (u16*)(wsw);
    u16* WQt_l = (u16*)(wsw + 524288);
    u16* WVt_h = (u16*)(wsw + 2 * 524288);
    u16* WVt_l = (u16*)(wsw + 3 * 524288);
    u16* WUt_h = (u16*)(wsw + 4 * 524288);
    u16* WUt_l = (u16*)(wsw + 5 * 524288);

    presplit_x<<<2048, 256, 0, stream>>>(X, Xh, Xl);
    presplit_w<<<3072, 256, 0, stream>>>(WQ, WV, WU, WQt_h, WQt_l,
                                         WVt_h, WVt_l, WUt_h, WUt_l);
    gemm_mfma<<<dim3(64, 16), 256, 0, stream>>>(
        Xh, Xl, WQt_h, WQt_l, WVt_h, WVt_l, Qh, Ql, Vh, Vl, nullptr, 0);
    attn_mfma<<<dim3(512), 256, 0, stream>>>(Qh, Ql, Vh, Vl, Xh, Xl);
    gemm_mfma<<<dim3(64, 8), 256, 0, stream>>>(
        Xh, Xl, WUt_h, WUt_l, nullptr, nullptr,
        nullptr, nullptr, nullptr, nullptr, out, 1);
}